// Round 4
// baseline (1075.757 us; speedup 1.0000x reference)
//
#include <hip/hip_runtime.h>
#include <hip/hip_bf16.h>

// ---------- types / helpers ----------
typedef __bf16 bf16x8 __attribute__((ext_vector_type(8)));
typedef float  f32x4  __attribute__((ext_vector_type(4)));

__device__ __forceinline__ ushort f2bf(float f) {
    unsigned u = __float_as_uint(f);
    u += 0x7FFF + ((u >> 16) & 1);      // RNE
    return (ushort)(u >> 16);
}

// ---------- cast fp32 -> bf16 (x4 vectorized) ----------
__global__ void cast_bf16x4(const float4* __restrict__ x, ushort4* __restrict__ y, int n4) {
    int i = blockIdx.x * 256 + threadIdx.x;
    if (i < n4) {
        float4 v = x[i];
        y[i] = make_ushort4(f2bf(v.x), f2bf(v.y), f2bf(v.z), f2bf(v.w));
    }
}

// ---------- transpose + cast: W[K,N] fp32 -> Wt[N,K] bf16 ----------
__global__ __launch_bounds__(256) void transpose_cast(const float* __restrict__ W,
                                                      ushort* __restrict__ Wt,
                                                      int K, int N) {
    __shared__ float tile[32][33];
    int n0 = blockIdx.x * 32, k0 = blockIdx.y * 32;
    int tx = threadIdx.x & 31, ty = threadIdx.x >> 5;   // ty 0..7
#pragma unroll
    for (int i = 0; i < 32; i += 8)
        tile[ty + i][tx] = W[(size_t)(k0 + ty + i) * N + n0 + tx];
    __syncthreads();
#pragma unroll
    for (int i = 0; i < 32; i += 8)
        Wt[(size_t)(n0 + ty + i) * K + k0 + tx] = f2bf(tile[tx][ty + i]);
}

// ---------- bf16 GEMM: C[M,N] = A[M,K] * Bt[N,K]^T, fp32 acc ----------
// 128x128 tile, BK=32, 256 threads (4 waves, each 64x64 via 4x4 16x16x32 MFMA)
// Register-staged LDS. out_bf16 selects output element type.
__global__ __launch_bounds__(256) void gemm_bt(const ushort* __restrict__ A,
                                               const ushort* __restrict__ Bt0,
                                               const ushort* __restrict__ Bt1,
                                               void* __restrict__ C0v,
                                               void* __restrict__ C1v,
                                               int M, int N, int K, int out_bf16) {
    const ushort* Bt = blockIdx.z ? Bt1 : Bt0;
    void* Cv = blockIdx.z ? C1v : C0v;
    __shared__ __align__(16) ushort As[128 * 32];
    __shared__ __align__(16) ushort Bs[128 * 32];
    const int tid = threadIdx.x;
    const int m0 = blockIdx.y * 128, n0 = blockIdx.x * 128;

    const int r0 = tid >> 2, cc = (tid & 3) * 8;
    const ushort* ga0 = A  + (size_t)(m0 + r0)      * K + cc;
    const ushort* ga1 = A  + (size_t)(m0 + r0 + 64) * K + cc;
    const ushort* gb0 = Bt + (size_t)(n0 + r0)      * K + cc;
    const ushort* gb1 = Bt + (size_t)(n0 + r0 + 64) * K + cc;
    const int la0 = r0 * 32 + cc, la1 = (r0 + 64) * 32 + cc;

    const int lane = tid & 63;
    const int wid = tid >> 6;
    const int wr = (wid >> 1) * 64, wc = (wid & 1) * 64;
    const int fr = lane & 15, koff = (lane >> 4) * 8;

    f32x4 acc[4][4] = {};
    for (int k0 = 0; k0 < K; k0 += 32) {
        uint4 va0 = *(const uint4*)(ga0 + k0);
        uint4 va1 = *(const uint4*)(ga1 + k0);
        uint4 vb0 = *(const uint4*)(gb0 + k0);
        uint4 vb1 = *(const uint4*)(gb1 + k0);
        __syncthreads();               // previous iteration's LDS reads done
        *(uint4*)&As[la0] = va0;
        *(uint4*)&As[la1] = va1;
        *(uint4*)&Bs[la0] = vb0;
        *(uint4*)&Bs[la1] = vb1;
        __syncthreads();
        bf16x8 af[4], bf[4];
#pragma unroll
        for (int i = 0; i < 4; ++i) {
            af[i] = *(const bf16x8*)&As[(wr + i * 16 + fr) * 32 + koff];
            bf[i] = *(const bf16x8*)&Bs[(wc + i * 16 + fr) * 32 + koff];
        }
#pragma unroll
        for (int i = 0; i < 4; ++i)
#pragma unroll
            for (int j = 0; j < 4; ++j)
                acc[i][j] = __builtin_amdgcn_mfma_f32_16x16x32_bf16(af[i], bf[j], acc[i][j], 0, 0, 0);
    }
    const int rbase = (lane >> 4) * 4;
    if (out_bf16) {
        ushort* C = (ushort*)Cv;
#pragma unroll
        for (int i = 0; i < 4; ++i)
#pragma unroll
            for (int j = 0; j < 4; ++j)
#pragma unroll
                for (int r = 0; r < 4; ++r)
                    C[(size_t)(m0 + wr + i * 16 + rbase + r) * N + n0 + wc + j * 16 + fr] = f2bf(acc[i][j][r]);
    } else {
        float* C = (float*)Cv;
#pragma unroll
        for (int i = 0; i < 4; ++i)
#pragma unroll
            for (int j = 0; j < 4; ++j)
#pragma unroll
                for (int r = 0; r < 4; ++r)
                    C[(size_t)(m0 + wr + i * 16 + rbase + r) * N + n0 + wc + j * 16 + fr] = acc[i][j][r];
    }
}

// ---------- beta / g projections (N=12 each) + activations ----------
__global__ __launch_bounds__(256) void bg_kernel(const float* __restrict__ hs,
                                                 const float* __restrict__ Wb,
                                                 const float* __restrict__ Wa,
                                                 const float* __restrict__ A_log,
                                                 const float* __restrict__ dt_bias,
                                                 float* __restrict__ beta,
                                                 float* __restrict__ g) {
    __shared__ float xs[2048];
    int t = blockIdx.x;
    for (int i = threadIdx.x; i < 2048; i += 256) xs[i] = hs[(size_t)t * 2048 + i];
    __syncthreads();
    int w = threadIdx.x >> 6, l = threadIdx.x & 63;
#pragma unroll
    for (int i = 0; i < 6; ++i) {
        int d = w * 6 + i;          // 0..23
        int hh = d % 12;
        const float* W = (d < 12) ? Wb : Wa;
        float p = 0.f;
        for (int e = l; e < 2048; e += 64) p += xs[e] * W[e * 12 + hh];
#pragma unroll
        for (int m = 32; m >= 1; m >>= 1) p += __shfl_xor(p, m, 64);
        if (l == 0) {
            if (d < 12) {
                beta[t * 12 + hh] = 1.f / (1.f + expf(-p));
            } else {
                float xg = p + dt_bias[hh];
                float sp = (xg > 15.f) ? xg : log1pf(expf(xg));
                g[t * 12 + hh] = -expf(A_log[hh]) * sp;
            }
        }
    }
}

// ---------- causal conv(K=4) + SiLU + l2norm for q/k ----------
__global__ void convqk_kernel(const float* __restrict__ qproj, const float* __restrict__ kproj,
                              const float* __restrict__ cwq, const float* __restrict__ cwk,
                              float* __restrict__ qout, float* __restrict__ kout) {
    int t = blockIdx.x, h = blockIdx.y, which = blockIdx.z;
    const float* x = which ? kproj : qproj;
    const float* cw = which ? cwk : cwq;
    float* out = which ? kout : qout;
    int c = threadIdx.x;                 // 0..127
    int ch = h * 128 + c;
    float4 w = *(const float4*)(cw + (size_t)ch * 4);
    float y = w.w * x[(size_t)t * 1536 + ch];
    if (t >= 1) y += w.z * x[(size_t)(t - 1) * 1536 + ch];
    if (t >= 2) y += w.y * x[(size_t)(t - 2) * 1536 + ch];
    if (t >= 3) y += w.x * x[(size_t)(t - 3) * 1536 + ch];
    y = y / (1.f + __expf(-y));          // silu
    float ss = y * y;
#pragma unroll
    for (int m = 32; m >= 1; m >>= 1) ss += __shfl_xor(ss, m, 64);
    __shared__ float red[2];
    if ((threadIdx.x & 63) == 0) red[threadIdx.x >> 6] = ss;
    __syncthreads();
    float tot = red[0] + red[1];
    out[((size_t)t * 12 + h) * 128 + c] = y * rsqrtf(tot + 1e-6f);
}

// ---------- causal conv(K=4) + SiLU for v ----------
__global__ void convv_kernel(const float* __restrict__ vproj, const float* __restrict__ cwv,
                             float* __restrict__ vout) {
    int t = blockIdx.x, h = blockIdx.y;
    int c = threadIdx.x;                 // 0..255
    int ch = h * 256 + c;
    float4 w = *(const float4*)(cwv + (size_t)ch * 4);
    float y = w.w * vproj[(size_t)t * 3072 + ch];
    if (t >= 1) y += w.z * vproj[(size_t)(t - 1) * 3072 + ch];
    if (t >= 2) y += w.y * vproj[(size_t)(t - 2) * 3072 + ch];
    if (t >= 3) y += w.x * vproj[(size_t)(t - 3) * 3072 + ch];
    y = y / (1.f + __expf(-y));
    vout[((size_t)t * 12 + h) * 256 + c] = y;
}

// ---------- gated delta rule scan ----------
// 3072 independent (head, dv) column recurrences; 16 lanes per column (8 dk each),
// 4 columns per 64-thread block. grid = 12*64 = 768 blocks.
__global__ __launch_bounds__(64) void scan_kernel(const float* __restrict__ qn,
                                                  const float* __restrict__ kn,
                                                  const float* __restrict__ vv,
                                                  const float* __restrict__ gd,
                                                  const float* __restrict__ bt,
                                                  float* __restrict__ o) {
    const int b = blockIdx.x;
    const int h = b >> 6;
    const int dv = ((b & 63) << 2) + (threadIdx.x >> 4);
    const int s = threadIdx.x & 15;
    float S[8];
#pragma unroll
    for (int i = 0; i < 8; ++i) S[i] = 0.f;
    const float* kp = kn + h * 128 + s * 8;
    const float* qp = qn + h * 128 + s * 8;
    const float* vp = vv + h * 256 + dv;
    const float* gp = gd + h;
    const float* bp = bt + h;
    float* op = o + h * 256 + dv;
    for (int t = 0; t < 1024; ++t) {
        float4 ka = *(const float4*)kp;
        float4 kb = *(const float4*)(kp + 4);
        float4 qa = *(const float4*)qp;
        float4 qb = *(const float4*)(qp + 4);
        float vt = *vp, gt = *gp, bb = *bp;
        float decay = __expf(gt);
        float p = ka.x * S[0] + ka.y * S[1] + ka.z * S[2] + ka.w * S[3]
                + kb.x * S[4] + kb.y * S[5] + kb.z * S[6] + kb.w * S[7];
        p += __shfl_xor(p, 1, 16);
        p += __shfl_xor(p, 2, 16);
        p += __shfl_xor(p, 4, 16);
        p += __shfl_xor(p, 8, 16);
        float delta = (vt - decay * p) * bb;
        S[0] = decay * S[0] + ka.x * delta;
        S[1] = decay * S[1] + ka.y * delta;
        S[2] = decay * S[2] + ka.z * delta;
        S[3] = decay * S[3] + ka.w * delta;
        S[4] = decay * S[4] + kb.x * delta;
        S[5] = decay * S[5] + kb.y * delta;
        S[6] = decay * S[6] + kb.z * delta;
        S[7] = decay * S[7] + kb.w * delta;
        float oo = qa.x * S[0] + qa.y * S[1] + qa.z * S[2] + qa.w * S[3]
                 + qb.x * S[4] + qb.y * S[5] + qb.z * S[6] + qb.w * S[7];
        oo += __shfl_xor(oo, 1, 16);
        oo += __shfl_xor(oo, 2, 16);
        oo += __shfl_xor(oo, 4, 16);
        oo += __shfl_xor(oo, 8, 16);
        if (s == 0) *op = oo;
        kp += 1536; qp += 1536; vp += 3072; gp += 12; bp += 12; op += 3072;
    }
}

// ---------- RMSNorm * norm_w * silu(gate), bf16 out (feeds final bf16 GEMM) ----------
__global__ __launch_bounds__(256) void normgate_kernel(const float* __restrict__ o,
                                                       const float* __restrict__ gproj,
                                                       const float* __restrict__ norm_w,
                                                       ushort* __restrict__ on) {
    int t = blockIdx.x, h = blockIdx.y;
    int c = threadIdx.x;                 // 0..255
    float val = o[((size_t)t * 12 + h) * 256 + c];
    float ss = val * val;
#pragma unroll
    for (int m = 32; m >= 1; m >>= 1) ss += __shfl_xor(ss, m, 64);
    __shared__ float red[4];
    if ((threadIdx.x & 63) == 0) red[threadIdx.x >> 6] = ss;
    __syncthreads();
    float tot = red[0] + red[1] + red[2] + red[3];
    float rstd = rsqrtf(tot * (1.f / 256.f) + 1e-5f);
    float gg = gproj[(size_t)t * 3072 + h * 256 + c];
    float res = val * rstd * norm_w[c] * (gg / (1.f + __expf(-gg)));
    on[(size_t)t * 3072 + h * 256 + c] = f2bf(res);
}

// ---------- launch ----------
extern "C" void kernel_launch(void* const* d_in, const int* in_sizes, int n_in,
                              void* d_out, int out_size, void* d_ws, size_t ws_size,
                              hipStream_t stream) {
    const float* hs   = (const float*)d_in[0];   // [1024,2048]
    const float* Wq   = (const float*)d_in[1];   // [2048,1536]
    const float* Wk   = (const float*)d_in[2];
    const float* Wv   = (const float*)d_in[3];   // [2048,3072]
    const float* Wb   = (const float*)d_in[4];   // [2048,12]
    const float* Wa   = (const float*)d_in[5];
    const float* Wg   = (const float*)d_in[6];   // [2048,3072]
    const float* Wo   = (const float*)d_in[7];   // [3072,2048]
    const float* cwq  = (const float*)d_in[8];   // [1536,4]
    const float* cwk  = (const float*)d_in[9];
    const float* cwv  = (const float*)d_in[10];  // [3072,4]
    const float* A_log   = (const float*)d_in[11];
    const float* dt_bias = (const float*)d_in[12];
    const float* norm_w  = (const float*)d_in[13];
    float* out = (float*)d_out;                  // [1024,2048] fp32 (reference output dtype)

    char* w = (char*)d_ws;
    auto alloc = [&](size_t bytes) { char* p = w; w += (bytes + 255) & ~(size_t)255; return p; };
    ushort* hs_bf = (ushort*)alloc(1024 * 2048 * 2);
    ushort* WqT   = (ushort*)alloc((size_t)1536 * 2048 * 2);
    ushort* WkT   = (ushort*)alloc((size_t)1536 * 2048 * 2);
    ushort* WvT   = (ushort*)alloc((size_t)3072 * 2048 * 2);
    ushort* WgT   = (ushort*)alloc((size_t)3072 * 2048 * 2);
    ushort* WoT   = (ushort*)alloc((size_t)2048 * 3072 * 2);
    float* qproj  = (float*)alloc((size_t)1024 * 1536 * 4);
    float* kproj  = (float*)alloc((size_t)1024 * 1536 * 4);
    float* vproj  = (float*)alloc((size_t)1024 * 3072 * 4);
    float* gproj  = (float*)alloc((size_t)1024 * 3072 * 4);
    float* qn     = (float*)alloc((size_t)1024 * 1536 * 4);
    float* kn     = (float*)alloc((size_t)1024 * 1536 * 4);
    float* vn     = (float*)alloc((size_t)1024 * 3072 * 4);
    float* gdec   = (float*)alloc(1024 * 12 * 4);
    float* betab  = (float*)alloc(1024 * 12 * 4);
    float* ob     = (float*)alloc((size_t)1024 * 3072 * 4);
    ushort* onb   = (ushort*)alloc((size_t)1024 * 3072 * 2);
    (void)ws_size; (void)n_in; (void)in_sizes; (void)out_size;

    // casts / transposes
    cast_bf16x4<<<2048, 256, 0, stream>>>((const float4*)hs, (ushort4*)hs_bf, 1024 * 2048 / 4);
    transpose_cast<<<dim3(48, 64), 256, 0, stream>>>(Wq, WqT, 2048, 1536);
    transpose_cast<<<dim3(48, 64), 256, 0, stream>>>(Wk, WkT, 2048, 1536);
    transpose_cast<<<dim3(96, 64), 256, 0, stream>>>(Wv, WvT, 2048, 3072);
    transpose_cast<<<dim3(96, 64), 256, 0, stream>>>(Wg, WgT, 2048, 3072);
    transpose_cast<<<dim3(64, 96), 256, 0, stream>>>(Wo, WoT, 3072, 2048);

    // projections
    gemm_bt<<<dim3(12, 8, 2), 256, 0, stream>>>(hs_bf, WqT, WkT, qproj, kproj, 1024, 1536, 2048, 0);
    gemm_bt<<<dim3(24, 8, 2), 256, 0, stream>>>(hs_bf, WvT, WgT, vproj, gproj, 1024, 3072, 2048, 0);
    bg_kernel<<<1024, 256, 0, stream>>>(hs, Wb, Wa, A_log, dt_bias, betab, gdec);

    // conv + silu (+ l2norm for q/k)
    convqk_kernel<<<dim3(1024, 12, 2), 128, 0, stream>>>(qproj, kproj, cwq, cwk, qn, kn);
    convv_kernel<<<dim3(1024, 12), 256, 0, stream>>>(vproj, cwv, vn);

    // gated delta rule
    scan_kernel<<<768, 64, 0, stream>>>(qn, kn, vn, gdec, betab, ob);

    // norm + gate -> bf16 (A operand of final GEMM)
    normgate_kernel<<<dim3(1024, 12), 256, 0, stream>>>(ob, gproj, norm_w, onb);

    // output projection -> fp32 d_out
    gemm_bt<<<dim3(16, 8, 1), 256, 0, stream>>>(onb, WoT, WoT, (void*)out, (void*)out, 1024, 2048, 3072, 0);
}

// Round 5
// 1027.523 us; speedup vs baseline: 1.0469x; 1.0469x over previous
//
#include <hip/hip_runtime.h>
#include <hip/hip_bf16.h>

// ---------- types / helpers ----------
typedef __bf16 bf16x8 __attribute__((ext_vector_type(8)));
typedef float  f32x4  __attribute__((ext_vector_type(4)));

__device__ __forceinline__ ushort f2bf(float f) {
    unsigned u = __float_as_uint(f);
    u += 0x7FFF + ((u >> 16) & 1);      // RNE
    return (ushort)(u >> 16);
}

// ---------- cast fp32 -> bf16 (x4 vectorized) ----------
__global__ void cast_bf16x4(const float4* __restrict__ x, ushort4* __restrict__ y, int n4) {
    int i = blockIdx.x * 256 + threadIdx.x;
    if (i < n4) {
        float4 v = x[i];
        y[i] = make_ushort4(f2bf(v.x), f2bf(v.y), f2bf(v.z), f2bf(v.w));
    }
}

// ---------- transpose + cast: W[K,N] fp32 -> Wt[N,K] bf16 ----------
__global__ __launch_bounds__(256) void transpose_cast(const float* __restrict__ W,
                                                      ushort* __restrict__ Wt,
                                                      int K, int N) {
    __shared__ float tile[32][33];
    int n0 = blockIdx.x * 32, k0 = blockIdx.y * 32;
    int tx = threadIdx.x & 31, ty = threadIdx.x >> 5;   // ty 0..7
#pragma unroll
    for (int i = 0; i < 32; i += 8)
        tile[ty + i][tx] = W[(size_t)(k0 + ty + i) * N + n0 + tx];
    __syncthreads();
#pragma unroll
    for (int i = 0; i < 32; i += 8)
        Wt[(size_t)(n0 + ty + i) * K + k0 + tx] = f2bf(tile[tx][ty + i]);
}

// ---------- bf16 GEMM: C[M,N] = A[M,K] * Bt[N,K]^T, fp32 acc ----------
// 128x128 tile, BK=32, 256 threads (4 waves, each 64x64 via 4x4 16x16x32 MFMA)
// Register-staged LDS. out_bf16 selects output element type.
__global__ __launch_bounds__(256) void gemm_bt(const ushort* __restrict__ A,
                                               const ushort* __restrict__ Bt0,
                                               const ushort* __restrict__ Bt1,
                                               void* __restrict__ C0v,
                                               void* __restrict__ C1v,
                                               int M, int N, int K, int out_bf16) {
    const ushort* Bt = blockIdx.z ? Bt1 : Bt0;
    void* Cv = blockIdx.z ? C1v : C0v;
    __shared__ __align__(16) ushort As[128 * 32];
    __shared__ __align__(16) ushort Bs[128 * 32];
    const int tid = threadIdx.x;
    const int m0 = blockIdx.y * 128, n0 = blockIdx.x * 128;

    const int r0 = tid >> 2, cc = (tid & 3) * 8;
    const ushort* ga0 = A  + (size_t)(m0 + r0)      * K + cc;
    const ushort* ga1 = A  + (size_t)(m0 + r0 + 64) * K + cc;
    const ushort* gb0 = Bt + (size_t)(n0 + r0)      * K + cc;
    const ushort* gb1 = Bt + (size_t)(n0 + r0 + 64) * K + cc;
    const int la0 = r0 * 32 + cc, la1 = (r0 + 64) * 32 + cc;

    const int lane = tid & 63;
    const int wid = tid >> 6;
    const int wr = (wid >> 1) * 64, wc = (wid & 1) * 64;
    const int fr = lane & 15, koff = (lane >> 4) * 8;

    f32x4 acc[4][4] = {};
    for (int k0 = 0; k0 < K; k0 += 32) {
        uint4 va0 = *(const uint4*)(ga0 + k0);
        uint4 va1 = *(const uint4*)(ga1 + k0);
        uint4 vb0 = *(const uint4*)(gb0 + k0);
        uint4 vb1 = *(const uint4*)(gb1 + k0);
        __syncthreads();               // previous iteration's LDS reads done
        *(uint4*)&As[la0] = va0;
        *(uint4*)&As[la1] = va1;
        *(uint4*)&Bs[la0] = vb0;
        *(uint4*)&Bs[la1] = vb1;
        __syncthreads();
        bf16x8 af[4], bf[4];
#pragma unroll
        for (int i = 0; i < 4; ++i) {
            af[i] = *(const bf16x8*)&As[(wr + i * 16 + fr) * 32 + koff];
            bf[i] = *(const bf16x8*)&Bs[(wc + i * 16 + fr) * 32 + koff];
        }
#pragma unroll
        for (int i = 0; i < 4; ++i)
#pragma unroll
            for (int j = 0; j < 4; ++j)
                acc[i][j] = __builtin_amdgcn_mfma_f32_16x16x32_bf16(af[i], bf[j], acc[i][j], 0, 0, 0);
    }
    const int rbase = (lane >> 4) * 4;
    if (out_bf16) {
        ushort* C = (ushort*)Cv;
#pragma unroll
        for (int i = 0; i < 4; ++i)
#pragma unroll
            for (int j = 0; j < 4; ++j)
#pragma unroll
                for (int r = 0; r < 4; ++r)
                    C[(size_t)(m0 + wr + i * 16 + rbase + r) * N + n0 + wc + j * 16 + fr] = f2bf(acc[i][j][r]);
    } else {
        float* C = (float*)Cv;
#pragma unroll
        for (int i = 0; i < 4; ++i)
#pragma unroll
            for (int j = 0; j < 4; ++j)
#pragma unroll
                for (int r = 0; r < 4; ++r)
                    C[(size_t)(m0 + wr + i * 16 + rbase + r) * N + n0 + wc + j * 16 + fr] = acc[i][j][r];
    }
}

// ---------- beta / g projections (N=12 each) + activations ----------
__global__ __launch_bounds__(256) void bg_kernel(const float* __restrict__ hs,
                                                 const float* __restrict__ Wb,
                                                 const float* __restrict__ Wa,
                                                 const float* __restrict__ A_log,
                                                 const float* __restrict__ dt_bias,
                                                 float* __restrict__ beta,
                                                 float* __restrict__ g) {
    __shared__ float xs[2048];
    int t = blockIdx.x;
    for (int i = threadIdx.x; i < 2048; i += 256) xs[i] = hs[(size_t)t * 2048 + i];
    __syncthreads();
    int w = threadIdx.x >> 6, l = threadIdx.x & 63;
#pragma unroll
    for (int i = 0; i < 6; ++i) {
        int d = w * 6 + i;          // 0..23
        int hh = d % 12;
        const float* W = (d < 12) ? Wb : Wa;
        float p = 0.f;
        for (int e = l; e < 2048; e += 64) p += xs[e] * W[e * 12 + hh];
#pragma unroll
        for (int m = 32; m >= 1; m >>= 1) p += __shfl_xor(p, m, 64);
        if (l == 0) {
            if (d < 12) {
                beta[t * 12 + hh] = 1.f / (1.f + expf(-p));
            } else {
                float xg = p + dt_bias[hh];
                float sp = (xg > 15.f) ? xg : log1pf(expf(xg));
                g[t * 12 + hh] = -expf(A_log[hh]) * sp;
            }
        }
    }
}

// ---------- causal conv(K=4) + SiLU + l2norm for q/k ----------
__global__ void convqk_kernel(const float* __restrict__ qproj, const float* __restrict__ kproj,
                              const float* __restrict__ cwq, const float* __restrict__ cwk,
                              float* __restrict__ qout, float* __restrict__ kout) {
    int t = blockIdx.x, h = blockIdx.y, which = blockIdx.z;
    const float* x = which ? kproj : qproj;
    const float* cw = which ? cwk : cwq;
    float* out = which ? kout : qout;
    int c = threadIdx.x;                 // 0..127
    int ch = h * 128 + c;
    float4 w = *(const float4*)(cw + (size_t)ch * 4);
    float y = w.w * x[(size_t)t * 1536 + ch];
    if (t >= 1) y += w.z * x[(size_t)(t - 1) * 1536 + ch];
    if (t >= 2) y += w.y * x[(size_t)(t - 2) * 1536 + ch];
    if (t >= 3) y += w.x * x[(size_t)(t - 3) * 1536 + ch];
    y = y / (1.f + __expf(-y));          // silu
    float ss = y * y;
#pragma unroll
    for (int m = 32; m >= 1; m >>= 1) ss += __shfl_xor(ss, m, 64);
    __shared__ float red[2];
    if ((threadIdx.x & 63) == 0) red[threadIdx.x >> 6] = ss;
    __syncthreads();
    float tot = red[0] + red[1];
    out[((size_t)t * 12 + h) * 128 + c] = y * rsqrtf(tot + 1e-6f);
}

// ---------- causal conv(K=4) + SiLU for v ----------
__global__ void convv_kernel(const float* __restrict__ vproj, const float* __restrict__ cwv,
                             float* __restrict__ vout) {
    int t = blockIdx.x, h = blockIdx.y;
    int c = threadIdx.x;                 // 0..255
    int ch = h * 256 + c;
    float4 w = *(const float4*)(cwv + (size_t)ch * 4);
    float y = w.w * vproj[(size_t)t * 3072 + ch];
    if (t >= 1) y += w.z * vproj[(size_t)(t - 1) * 3072 + ch];
    if (t >= 2) y += w.y * vproj[(size_t)(t - 2) * 3072 + ch];
    if (t >= 3) y += w.x * vproj[(size_t)(t - 3) * 3072 + ch];
    y = y / (1.f + __expf(-y));
    vout[((size_t)t * 12 + h) * 256 + c] = y;
}

// ---------- gated delta rule scan (v2: 32 lanes/column + depth-2 prefetch) ----------
// 3072 independent (head, dv) column recurrences; 32 lanes per column (4 dk each),
// 2 columns per 64-thread wave. grid = 12*128 = 1536 one-wave blocks.
// Next-next timestep's inputs are loaded into named registers while computing the
// current step, taking global-load latency off the serial critical path.
__global__ __launch_bounds__(64) void scan_kernel(const float* __restrict__ qn,
                                                  const float* __restrict__ kn,
                                                  const float* __restrict__ vv,
                                                  const float* __restrict__ gd,
                                                  const float* __restrict__ bt,
                                                  float* __restrict__ o) {
    const int b = blockIdx.x;
    const int h = b >> 7;                       // 128 column-pairs per head
    const int pair = b & 127;
    const int grp = threadIdx.x >> 5;           // 0,1 -> column within pair
    const int s = threadIdx.x & 31;             // dk slice of 4
    const int dv = (pair << 1) + grp;

    const float* kp = kn + h * 128 + s * 4;     // stride 1536 per t
    const float* qp = qn + h * 128 + s * 4;
    const float* vp = vv + h * 256 + dv;        // stride 3072
    const float* gp = gd + h;                   // stride 12
    const float* bp = bt + h;
    float* op = o + h * 256 + dv;               // stride 3072

    float S0 = 0.f, S1 = 0.f, S2 = 0.f, S3 = 0.f;

    // prefetch t=0 (current) and t=1 (next)
    float4 kc = *(const float4*)(kp);
    float4 qc = *(const float4*)(qp);
    float  vc = vp[0], gc = gp[0], bc = bp[0];
    float4 kx = *(const float4*)(kp + 1536);
    float4 qx = *(const float4*)(qp + 1536);
    float  vx = vp[3072], gx = gp[12], bx = bp[12];

    for (int t = 0; t < 1024; ++t) {
        // issue loads for t+2 (clamped) before touching the dependent chain
        int tn = t + 2 < 1024 ? t + 2 : 1023;
        float4 k2 = *(const float4*)(kp + (size_t)tn * 1536);
        float4 q2 = *(const float4*)(qp + (size_t)tn * 1536);
        float  v2 = vp[(size_t)tn * 3072];
        float  g2 = gp[(size_t)tn * 12];
        float  b2 = bp[(size_t)tn * 12];

        float decay = __expf(gc);
        float p = kc.x * S0 + kc.y * S1 + kc.z * S2 + kc.w * S3;
        p += __shfl_xor(p, 1, 32);
        p += __shfl_xor(p, 2, 32);
        p += __shfl_xor(p, 4, 32);
        p += __shfl_xor(p, 8, 32);
        p += __shfl_xor(p, 16, 32);
        float delta = (vc - decay * p) * bc;
        S0 = decay * S0 + kc.x * delta;
        S1 = decay * S1 + kc.y * delta;
        S2 = decay * S2 + kc.z * delta;
        S3 = decay * S3 + kc.w * delta;
        float oo = qc.x * S0 + qc.y * S1 + qc.z * S2 + qc.w * S3;
        oo += __shfl_xor(oo, 1, 32);
        oo += __shfl_xor(oo, 2, 32);
        oo += __shfl_xor(oo, 4, 32);
        oo += __shfl_xor(oo, 8, 32);
        oo += __shfl_xor(oo, 16, 32);
        if (s == 0) op[(size_t)t * 3072] = oo;

        // rotate prefetch registers
        kc = kx; qc = qx; vc = vx; gc = gx; bc = bx;
        kx = k2; qx = q2; vx = v2; gx = g2; bx = b2;
    }
}

// ---------- RMSNorm * norm_w * silu(gate), bf16 out (feeds final bf16 GEMM) ----------
__global__ __launch_bounds__(256) void normgate_kernel(const float* __restrict__ o,
                                                       const float* __restrict__ gproj,
                                                       const float* __restrict__ norm_w,
                                                       ushort* __restrict__ on) {
    int t = blockIdx.x, h = blockIdx.y;
    int c = threadIdx.x;                 // 0..255
    float val = o[((size_t)t * 12 + h) * 256 + c];
    float ss = val * val;
#pragma unroll
    for (int m = 32; m >= 1; m >>= 1) ss += __shfl_xor(ss, m, 64);
    __shared__ float red[4];
    if ((threadIdx.x & 63) == 0) red[threadIdx.x >> 6] = ss;
    __syncthreads();
    float tot = red[0] + red[1] + red[2] + red[3];
    float rstd = rsqrtf(tot * (1.f / 256.f) + 1e-5f);
    float gg = gproj[(size_t)t * 3072 + h * 256 + c];
    float res = val * rstd * norm_w[c] * (gg / (1.f + __expf(-gg)));
    on[(size_t)t * 3072 + h * 256 + c] = f2bf(res);
}

// ---------- launch ----------
extern "C" void kernel_launch(void* const* d_in, const int* in_sizes, int n_in,
                              void* d_out, int out_size, void* d_ws, size_t ws_size,
                              hipStream_t stream) {
    const float* hs   = (const float*)d_in[0];   // [1024,2048]
    const float* Wq   = (const float*)d_in[1];   // [2048,1536]
    const float* Wk   = (const float*)d_in[2];
    const float* Wv   = (const float*)d_in[3];   // [2048,3072]
    const float* Wb   = (const float*)d_in[4];   // [2048,12]
    const float* Wa   = (const float*)d_in[5];
    const float* Wg   = (const float*)d_in[6];   // [2048,3072]
    const float* Wo   = (const float*)d_in[7];   // [3072,2048]
    const float* cwq  = (const float*)d_in[8];   // [1536,4]
    const float* cwk  = (const float*)d_in[9];
    const float* cwv  = (const float*)d_in[10];  // [3072,4]
    const float* A_log   = (const float*)d_in[11];
    const float* dt_bias = (const float*)d_in[12];
    const float* norm_w  = (const float*)d_in[13];
    float* out = (float*)d_out;                  // [1024,2048] fp32 (reference output dtype)

    char* w = (char*)d_ws;
    auto alloc = [&](size_t bytes) { char* p = w; w += (bytes + 255) & ~(size_t)255; return p; };
    ushort* hs_bf = (ushort*)alloc(1024 * 2048 * 2);
    ushort* WqT   = (ushort*)alloc((size_t)1536 * 2048 * 2);
    ushort* WkT   = (ushort*)alloc((size_t)1536 * 2048 * 2);
    ushort* WvT   = (ushort*)alloc((size_t)3072 * 2048 * 2);
    ushort* WgT   = (ushort*)alloc((size_t)3072 * 2048 * 2);
    ushort* WoT   = (ushort*)alloc((size_t)2048 * 3072 * 2);
    float* qproj  = (float*)alloc((size_t)1024 * 1536 * 4);
    float* kproj  = (float*)alloc((size_t)1024 * 1536 * 4);
    float* vproj  = (float*)alloc((size_t)1024 * 3072 * 4);
    float* gproj  = (float*)alloc((size_t)1024 * 3072 * 4);
    float* qn     = (float*)alloc((size_t)1024 * 1536 * 4);
    float* kn     = (float*)alloc((size_t)1024 * 1536 * 4);
    float* vn     = (float*)alloc((size_t)1024 * 3072 * 4);
    float* gdec   = (float*)alloc(1024 * 12 * 4);
    float* betab  = (float*)alloc(1024 * 12 * 4);
    float* ob     = (float*)alloc((size_t)1024 * 3072 * 4);
    ushort* onb   = (ushort*)alloc((size_t)1024 * 3072 * 2);
    (void)ws_size; (void)n_in; (void)in_sizes; (void)out_size;

    // casts / transposes
    cast_bf16x4<<<2048, 256, 0, stream>>>((const float4*)hs, (ushort4*)hs_bf, 1024 * 2048 / 4);
    transpose_cast<<<dim3(48, 64), 256, 0, stream>>>(Wq, WqT, 2048, 1536);
    transpose_cast<<<dim3(48, 64), 256, 0, stream>>>(Wk, WkT, 2048, 1536);
    transpose_cast<<<dim3(96, 64), 256, 0, stream>>>(Wv, WvT, 2048, 3072);
    transpose_cast<<<dim3(96, 64), 256, 0, stream>>>(Wg, WgT, 2048, 3072);
    transpose_cast<<<dim3(64, 96), 256, 0, stream>>>(Wo, WoT, 3072, 2048);

    // projections
    gemm_bt<<<dim3(12, 8, 2), 256, 0, stream>>>(hs_bf, WqT, WkT, qproj, kproj, 1024, 1536, 2048, 0);
    gemm_bt<<<dim3(24, 8, 2), 256, 0, stream>>>(hs_bf, WvT, WgT, vproj, gproj, 1024, 3072, 2048, 0);
    bg_kernel<<<1024, 256, 0, stream>>>(hs, Wb, Wa, A_log, dt_bias, betab, gdec);

    // conv + silu (+ l2norm for q/k)
    convqk_kernel<<<dim3(1024, 12, 2), 128, 0, stream>>>(qproj, kproj, cwq, cwk, qn, kn);
    convv_kernel<<<dim3(1024, 12), 256, 0, stream>>>(vproj, cwv, vn);

    // gated delta rule
    scan_kernel<<<1536, 64, 0, stream>>>(qn, kn, vn, gdec, betab, ob);

    // norm + gate -> bf16 (A operand of final GEMM)
    normgate_kernel<<<dim3(1024, 12), 256, 0, stream>>>(ob, gproj, norm_w, onb);

    // output projection -> fp32 d_out
    gemm_bt<<<dim3(16, 8, 1), 256, 0, stream>>>(onb, WoT, WoT, (void*)out, (void*)out, 1024, 2048, 3072, 0);
}

// Round 6
// 861.754 us; speedup vs baseline: 1.2483x; 1.1924x over previous
//
#include <hip/hip_runtime.h>
#include <hip/hip_bf16.h>

// ---------- types / helpers ----------
typedef __bf16 bf16x8 __attribute__((ext_vector_type(8)));
typedef float  f32x4  __attribute__((ext_vector_type(4)));

__device__ __forceinline__ ushort f2bf(float f) {
    unsigned u = __float_as_uint(f);
    u += 0x7FFF + ((u >> 16) & 1);      // RNE
    return (ushort)(u >> 16);
}

// DPP-based sum across 16-lane group (VALU only, no DS on the critical path)
template <int CTRL>
__device__ __forceinline__ float dppadd(float x) {
    int y = __builtin_amdgcn_update_dpp(0, __float_as_int(x), CTRL, 0xF, 0xF, true);
    return x + __int_as_float(y);
}
__device__ __forceinline__ float red16(float x) {
    x = dppadd<0xB1>(x);    // quad_perm [1,0,3,2]  : xor 1
    x = dppadd<0x4E>(x);    // quad_perm [2,3,0,1]  : xor 2
    x = dppadd<0x141>(x);   // row_half_mirror      : combine 4s within 8
    x = dppadd<0x140>(x);   // row_mirror           : combine 8s within 16
    return x;
}

// ---------- cast fp32 -> bf16 (x4 vectorized) ----------
__global__ void cast_bf16x4(const float4* __restrict__ x, ushort4* __restrict__ y, int n4) {
    int i = blockIdx.x * 256 + threadIdx.x;
    if (i < n4) {
        float4 v = x[i];
        y[i] = make_ushort4(f2bf(v.x), f2bf(v.y), f2bf(v.z), f2bf(v.w));
    }
}

// ---------- transpose + cast: W[K,N] fp32 -> Wt[N,K] bf16 ----------
__global__ __launch_bounds__(256) void transpose_cast(const float* __restrict__ W,
                                                      ushort* __restrict__ Wt,
                                                      int K, int N) {
    __shared__ float tile[32][33];
    int n0 = blockIdx.x * 32, k0 = blockIdx.y * 32;
    int tx = threadIdx.x & 31, ty = threadIdx.x >> 5;   // ty 0..7
#pragma unroll
    for (int i = 0; i < 32; i += 8)
        tile[ty + i][tx] = W[(size_t)(k0 + ty + i) * N + n0 + tx];
    __syncthreads();
#pragma unroll
    for (int i = 0; i < 32; i += 8)
        Wt[(size_t)(n0 + ty + i) * K + k0 + tx] = f2bf(tile[tx][ty + i]);
}

// ---------- bf16 GEMM: C[M,N] = A[M,K] * Bt[N,K]^T, fp32 acc ----------
// 128x128 tile, BK=32, 256 threads (4 waves, each 64x64 via 4x4 16x16x32 MFMA)
__global__ __launch_bounds__(256) void gemm_bt(const ushort* __restrict__ A,
                                               const ushort* __restrict__ Bt0,
                                               const ushort* __restrict__ Bt1,
                                               void* __restrict__ C0v,
                                               void* __restrict__ C1v,
                                               int M, int N, int K, int out_bf16) {
    const ushort* Bt = blockIdx.z ? Bt1 : Bt0;
    void* Cv = blockIdx.z ? C1v : C0v;
    __shared__ __align__(16) ushort As[128 * 32];
    __shared__ __align__(16) ushort Bs[128 * 32];
    const int tid = threadIdx.x;
    const int m0 = blockIdx.y * 128, n0 = blockIdx.x * 128;

    const int r0 = tid >> 2, cc = (tid & 3) * 8;
    const ushort* ga0 = A  + (size_t)(m0 + r0)      * K + cc;
    const ushort* ga1 = A  + (size_t)(m0 + r0 + 64) * K + cc;
    const ushort* gb0 = Bt + (size_t)(n0 + r0)      * K + cc;
    const ushort* gb1 = Bt + (size_t)(n0 + r0 + 64) * K + cc;
    const int la0 = r0 * 32 + cc, la1 = (r0 + 64) * 32 + cc;

    const int lane = tid & 63;
    const int wid = tid >> 6;
    const int wr = (wid >> 1) * 64, wc = (wid & 1) * 64;
    const int fr = lane & 15, koff = (lane >> 4) * 8;

    f32x4 acc[4][4] = {};
    for (int k0 = 0; k0 < K; k0 += 32) {
        uint4 va0 = *(const uint4*)(ga0 + k0);
        uint4 va1 = *(const uint4*)(ga1 + k0);
        uint4 vb0 = *(const uint4*)(gb0 + k0);
        uint4 vb1 = *(const uint4*)(gb1 + k0);
        __syncthreads();               // previous iteration's LDS reads done
        *(uint4*)&As[la0] = va0;
        *(uint4*)&As[la1] = va1;
        *(uint4*)&Bs[la0] = vb0;
        *(uint4*)&Bs[la1] = vb1;
        __syncthreads();
        bf16x8 af[4], bf[4];
#pragma unroll
        for (int i = 0; i < 4; ++i) {
            af[i] = *(const bf16x8*)&As[(wr + i * 16 + fr) * 32 + koff];
            bf[i] = *(const bf16x8*)&Bs[(wc + i * 16 + fr) * 32 + koff];
        }
#pragma unroll
        for (int i = 0; i < 4; ++i)
#pragma unroll
            for (int j = 0; j < 4; ++j)
                acc[i][j] = __builtin_amdgcn_mfma_f32_16x16x32_bf16(af[i], bf[j], acc[i][j], 0, 0, 0);
    }
    const int rbase = (lane >> 4) * 4;
    if (out_bf16) {
        ushort* C = (ushort*)Cv;
#pragma unroll
        for (int i = 0; i < 4; ++i)
#pragma unroll
            for (int j = 0; j < 4; ++j)
#pragma unroll
                for (int r = 0; r < 4; ++r)
                    C[(size_t)(m0 + wr + i * 16 + rbase + r) * N + n0 + wc + j * 16 + fr] = f2bf(acc[i][j][r]);
    } else {
        float* C = (float*)Cv;
#pragma unroll
        for (int i = 0; i < 4; ++i)
#pragma unroll
            for (int j = 0; j < 4; ++j)
#pragma unroll
                for (int r = 0; r < 4; ++r)
                    C[(size_t)(m0 + wr + i * 16 + rbase + r) * N + n0 + wc + j * 16 + fr] = acc[i][j][r];
    }
}

// ---------- beta / g projections (N=12 each) + activations ----------
__global__ __launch_bounds__(256) void bg_kernel(const float* __restrict__ hs,
                                                 const float* __restrict__ Wb,
                                                 const float* __restrict__ Wa,
                                                 const float* __restrict__ A_log,
                                                 const float* __restrict__ dt_bias,
                                                 float* __restrict__ beta,
                                                 float* __restrict__ g) {
    __shared__ float xs[2048];
    int t = blockIdx.x;
    for (int i = threadIdx.x; i < 2048; i += 256) xs[i] = hs[(size_t)t * 2048 + i];
    __syncthreads();
    int w = threadIdx.x >> 6, l = threadIdx.x & 63;
#pragma unroll
    for (int i = 0; i < 6; ++i) {
        int d = w * 6 + i;          // 0..23
        int hh = d % 12;
        const float* W = (d < 12) ? Wb : Wa;
        float p = 0.f;
        for (int e = l; e < 2048; e += 64) p += xs[e] * W[e * 12 + hh];
#pragma unroll
        for (int m = 32; m >= 1; m >>= 1) p += __shfl_xor(p, m, 64);
        if (l == 0) {
            if (d < 12) {
                beta[t * 12 + hh] = 1.f / (1.f + expf(-p));
            } else {
                float xg = p + dt_bias[hh];
                float sp = (xg > 15.f) ? xg : log1pf(expf(xg));
                g[t * 12 + hh] = -expf(A_log[hh]) * sp;
            }
        }
    }
}

// ---------- causal conv(K=4) + SiLU + l2norm for q/k (reads merged proj) ----------
__global__ void convqk_kernel(const float* __restrict__ proj,
                              const float* __restrict__ cwq, const float* __restrict__ cwk,
                              float* __restrict__ qout, float* __restrict__ kout) {
    int t = blockIdx.x, h = blockIdx.y, which = blockIdx.z;
    const float* x = proj + which * 1536;       // q at col 0, k at col 1536
    const float* cw = which ? cwk : cwq;
    float* out = which ? kout : qout;
    int c = threadIdx.x;                 // 0..127
    int ch = h * 128 + c;
    float4 w = *(const float4*)(cw + (size_t)ch * 4);
    float y = w.w * x[(size_t)t * 9216 + ch];
    if (t >= 1) y += w.z * x[(size_t)(t - 1) * 9216 + ch];
    if (t >= 2) y += w.y * x[(size_t)(t - 2) * 9216 + ch];
    if (t >= 3) y += w.x * x[(size_t)(t - 3) * 9216 + ch];
    y = y / (1.f + __expf(-y));          // silu
    float ss = y * y;
#pragma unroll
    for (int m = 32; m >= 1; m >>= 1) ss += __shfl_xor(ss, m, 64);
    __shared__ float red[2];
    if ((threadIdx.x & 63) == 0) red[threadIdx.x >> 6] = ss;
    __syncthreads();
    float tot = red[0] + red[1];
    out[((size_t)t * 12 + h) * 128 + c] = y * rsqrtf(tot + 1e-6f);
}

// ---------- causal conv(K=4) + SiLU for v (reads merged proj at col 3072) ----------
__global__ void convv_kernel(const float* __restrict__ proj, const float* __restrict__ cwv,
                             float* __restrict__ vout) {
    int t = blockIdx.x, h = blockIdx.y;
    const float* x = proj + 3072;
    int c = threadIdx.x;                 // 0..255
    int ch = h * 256 + c;
    float4 w = *(const float4*)(cwv + (size_t)ch * 4);
    float y = w.w * x[(size_t)t * 9216 + ch];
    if (t >= 1) y += w.z * x[(size_t)(t - 1) * 9216 + ch];
    if (t >= 2) y += w.y * x[(size_t)(t - 2) * 9216 + ch];
    if (t >= 3) y += w.x * x[(size_t)(t - 3) * 9216 + ch];
    y = y / (1.f + __expf(-y));
    vout[((size_t)t * 12 + h) * 256 + c] = y;
}

// ---------- gated delta rule scan (v3: DPP reduction, depth-4 static pipeline) ----------
// 3072 (head, dv) column recurrences; 16 lanes/column (8 dk each), 4 columns/wave.
// grid = 12*64 = 768 one-wave blocks. Reductions are DPP (VALU) — no DS latency
// on the serial chain. Loads for t+4 issue at the end of step t (3 steps of cover).
__global__ __launch_bounds__(64) void scan_kernel(const float* __restrict__ qn,
                                                  const float* __restrict__ kn,
                                                  const float* __restrict__ vv,
                                                  const float* __restrict__ gd,
                                                  const float* __restrict__ bt,
                                                  float* __restrict__ o) {
    const int b = blockIdx.x;
    const int h = b >> 6;
    const int quad = b & 63;
    const int grp = threadIdx.x >> 4;           // 0..3: column within quad
    const int l16 = threadIdx.x & 15;           // dk slice of 8
    const int dv = quad * 4 + grp;

    const float* kp = kn + h * 128 + l16 * 8;   // stride 1536 per t
    const float* qp = qn + h * 128 + l16 * 8;
    const float* vp = vv + h * 256 + dv;        // stride 3072
    const float* gp = gd + h;                   // stride 12
    const float* bp = bt + h;
    float* op = o + h * 256 + dv;               // stride 3072

    float S0 = 0.f, S1 = 0.f, S2 = 0.f, S3 = 0.f, S4 = 0.f, S5 = 0.f, S6 = 0.f, S7 = 0.f;
    float4 Aka, Akb, Aqa, Aqb; float Av, Ag, Ab;
    float4 Bka, Bkb, Bqa, Bqb; float Bv, Bg, Bb;
    float4 Cka, Ckb, Cqa, Cqb; float Cv, Cg, Cb;
    float4 Dka, Dkb, Dqa, Dqb; float Dv, Dg, Db;

#define LOADSLOT(P, T) { int _t = (T) < 1024 ? (T) : 1023; size_t _r = (size_t)_t * 1536; \
    P##ka = *(const float4*)(kp + _r); P##kb = *(const float4*)(kp + _r + 4); \
    P##qa = *(const float4*)(qp + _r); P##qb = *(const float4*)(qp + _r + 4); \
    P##v = vp[(size_t)_t * 3072]; P##g = gp[(size_t)_t * 12]; P##b = bp[(size_t)_t * 12]; }

#define STEP(P, T, TL) { \
    float d = __expf(P##g); \
    float vb = P##v * P##b, db = d * P##b; \
    float p01 = P##ka.x * S0 + P##ka.y * S1; \
    float p23 = P##ka.z * S2 + P##ka.w * S3; \
    float p45 = P##kb.x * S4 + P##kb.y * S5; \
    float p67 = P##kb.z * S6 + P##kb.w * S7; \
    float p = red16((p01 + p23) + (p45 + p67)); \
    float delta = vb - db * p; \
    S0 = d * S0 + P##ka.x * delta; S1 = d * S1 + P##ka.y * delta; \
    S2 = d * S2 + P##ka.z * delta; S3 = d * S3 + P##ka.w * delta; \
    S4 = d * S4 + P##kb.x * delta; S5 = d * S5 + P##kb.y * delta; \
    S6 = d * S6 + P##kb.z * delta; S7 = d * S7 + P##kb.w * delta; \
    float o01 = P##qa.x * S0 + P##qa.y * S1; \
    float o23 = P##qa.z * S2 + P##qa.w * S3; \
    float o45 = P##qb.x * S4 + P##qb.y * S5; \
    float o67 = P##qb.z * S6 + P##qb.w * S7; \
    float oo = red16((o01 + o23) + (o45 + o67)); \
    if (l16 == 0) op[(size_t)(T) * 3072] = oo; \
    LOADSLOT(P, TL) }

    LOADSLOT(A, 0) LOADSLOT(B, 1) LOADSLOT(C, 2) LOADSLOT(D, 3)
    for (int t = 0; t < 1024; t += 4) {
        STEP(A, t,     t + 4)
        STEP(B, t + 1, t + 5)
        STEP(C, t + 2, t + 6)
        STEP(D, t + 3, t + 7)
    }
#undef STEP
#undef LOADSLOT
}

// ---------- RMSNorm * norm_w * silu(gate), bf16 out (gate from merged proj col 6144) ----------
__global__ __launch_bounds__(256) void normgate_kernel(const float* __restrict__ o,
                                                       const float* __restrict__ proj,
                                                       const float* __restrict__ norm_w,
                                                       ushort* __restrict__ on) {
    int t = blockIdx.x, h = blockIdx.y;
    int c = threadIdx.x;                 // 0..255
    float val = o[((size_t)t * 12 + h) * 256 + c];
    float ss = val * val;
#pragma unroll
    for (int m = 32; m >= 1; m >>= 1) ss += __shfl_xor(ss, m, 64);
    __shared__ float red[4];
    if ((threadIdx.x & 63) == 0) red[threadIdx.x >> 6] = ss;
    __syncthreads();
    float tot = red[0] + red[1] + red[2] + red[3];
    float rstd = rsqrtf(tot * (1.f / 256.f) + 1e-5f);
    float gg = proj[(size_t)t * 9216 + 6144 + h * 256 + c];
    float res = val * rstd * norm_w[c] * (gg / (1.f + __expf(-gg)));
    on[(size_t)t * 3072 + h * 256 + c] = f2bf(res);
}

// ---------- launch ----------
extern "C" void kernel_launch(void* const* d_in, const int* in_sizes, int n_in,
                              void* d_out, int out_size, void* d_ws, size_t ws_size,
                              hipStream_t stream) {
    const float* hs   = (const float*)d_in[0];   // [1024,2048]
    const float* Wq   = (const float*)d_in[1];   // [2048,1536]
    const float* Wk   = (const float*)d_in[2];
    const float* Wv   = (const float*)d_in[3];   // [2048,3072]
    const float* Wb   = (const float*)d_in[4];   // [2048,12]
    const float* Wa   = (const float*)d_in[5];
    const float* Wg   = (const float*)d_in[6];   // [2048,3072]
    const float* Wo   = (const float*)d_in[7];   // [3072,2048]
    const float* cwq  = (const float*)d_in[8];   // [1536,4]
    const float* cwk  = (const float*)d_in[9];
    const float* cwv  = (const float*)d_in[10];  // [3072,4]
    const float* A_log   = (const float*)d_in[11];
    const float* dt_bias = (const float*)d_in[12];
    const float* norm_w  = (const float*)d_in[13];
    float* out = (float*)d_out;                  // [1024,2048] fp32

    char* w = (char*)d_ws;
    auto alloc = [&](size_t bytes) { char* p = w; w += (bytes + 255) & ~(size_t)255; return p; };
    ushort* hs_bf   = (ushort*)alloc(1024 * 2048 * 2);
    ushort* WqkvgT  = (ushort*)alloc((size_t)9216 * 2048 * 2);  // [q|k|v|g] rows
    ushort* WoT     = (ushort*)alloc((size_t)2048 * 3072 * 2);
    float* proj     = (float*)alloc((size_t)1024 * 9216 * 4);   // merged projections
    float* qn       = (float*)alloc((size_t)1024 * 1536 * 4);
    float* kn       = (float*)alloc((size_t)1024 * 1536 * 4);
    float* vn       = (float*)alloc((size_t)1024 * 3072 * 4);
    float* gdec     = (float*)alloc(1024 * 12 * 4);
    float* betab    = (float*)alloc(1024 * 12 * 4);
    float* ob       = (float*)alloc((size_t)1024 * 3072 * 4);
    ushort* onb     = (ushort*)alloc((size_t)1024 * 3072 * 2);
    (void)ws_size; (void)n_in; (void)in_sizes; (void)out_size;

    // casts / transposes (concatenated weight: q@0, k@1536, v@3072, g@6144)
    cast_bf16x4<<<2048, 256, 0, stream>>>((const float4*)hs, (ushort4*)hs_bf, 1024 * 2048 / 4);
    transpose_cast<<<dim3(48, 64), 256, 0, stream>>>(Wq, WqkvgT, 2048, 1536);
    transpose_cast<<<dim3(48, 64), 256, 0, stream>>>(Wk, WqkvgT + (size_t)1536 * 2048, 2048, 1536);
    transpose_cast<<<dim3(96, 64), 256, 0, stream>>>(Wv, WqkvgT + (size_t)3072 * 2048, 2048, 3072);
    transpose_cast<<<dim3(96, 64), 256, 0, stream>>>(Wg, WqkvgT + (size_t)6144 * 2048, 2048, 3072);
    transpose_cast<<<dim3(64, 96), 256, 0, stream>>>(Wo, WoT, 3072, 2048);

    // merged q/k/v/g projection: [1024,2048] x [2048,9216]
    gemm_bt<<<dim3(72, 8, 1), 256, 0, stream>>>(hs_bf, WqkvgT, WqkvgT, proj, proj, 1024, 9216, 2048, 0);
    bg_kernel<<<1024, 256, 0, stream>>>(hs, Wb, Wa, A_log, dt_bias, betab, gdec);

    // conv + silu (+ l2norm for q/k)
    convqk_kernel<<<dim3(1024, 12, 2), 128, 0, stream>>>(proj, cwq, cwk, qn, kn);
    convv_kernel<<<dim3(1024, 12), 256, 0, stream>>>(proj, cwv, vn);

    // gated delta rule
    scan_kernel<<<768, 64, 0, stream>>>(qn, kn, vn, gdec, betab, ob);

    // norm + gate -> bf16 (A operand of final GEMM)
    normgate_kernel<<<dim3(1024, 12), 256, 0, stream>>>(ob, proj, norm_w, onb);

    // output projection -> fp32 d_out
    gemm_bt<<<dim3(16, 8, 1), 256, 0, stream>>>(onb, WoT, WoT, (void*)out, (void*)out, 1024, 2048, 3072, 0);
}

// Round 8
// 732.547 us; speedup vs baseline: 1.4685x; 1.1764x over previous
//
#include <hip/hip_runtime.h>
#include <hip/hip_bf16.h>

// ---------- types / helpers ----------
typedef __bf16 bf16x8 __attribute__((ext_vector_type(8)));
typedef float  f32x4  __attribute__((ext_vector_type(4)));

__device__ __forceinline__ ushort f2bf(float f) {
    unsigned u = __float_as_uint(f);
    u += 0x7FFF + ((u >> 16) & 1);      // RNE
    return (ushort)(u >> 16);
}

// DPP-based sum across 16-lane group (VALU only, no DS on the critical path)
template <int CTRL>
__device__ __forceinline__ float dppadd(float x) {
    int y = __builtin_amdgcn_update_dpp(0, __float_as_int(x), CTRL, 0xF, 0xF, true);
    return x + __int_as_float(y);
}
__device__ __forceinline__ float red16(float x) {
    x = dppadd<0xB1>(x);    // quad_perm [1,0,3,2]  : xor 1
    x = dppadd<0x4E>(x);    // quad_perm [2,3,0,1]  : xor 2
    x = dppadd<0x141>(x);   // row_half_mirror      : combine 4s within 8
    x = dppadd<0x140>(x);   // row_mirror           : combine 8s within 16
    return x;
}

// ---------- cast fp32 -> bf16 (x4 vectorized) ----------
__global__ void cast_bf16x4(const float4* __restrict__ x, ushort4* __restrict__ y, int n4) {
    int i = blockIdx.x * 256 + threadIdx.x;
    if (i < n4) {
        float4 v = x[i];
        y[i] = make_ushort4(f2bf(v.x), f2bf(v.y), f2bf(v.z), f2bf(v.w));
    }
}

// ---------- transpose + cast: W[K,N] fp32 -> Wt[N,K] bf16 ----------
__global__ __launch_bounds__(256) void transpose_cast(const float* __restrict__ W,
                                                      ushort* __restrict__ Wt,
                                                      int K, int N) {
    __shared__ float tile[32][33];
    int n0 = blockIdx.x * 32, k0 = blockIdx.y * 32;
    int tx = threadIdx.x & 31, ty = threadIdx.x >> 5;   // ty 0..7
#pragma unroll
    for (int i = 0; i < 32; i += 8)
        tile[ty + i][tx] = W[(size_t)(k0 + ty + i) * N + n0 + tx];
    __syncthreads();
#pragma unroll
    for (int i = 0; i < 32; i += 8)
        Wt[(size_t)(n0 + ty + i) * K + k0 + tx] = f2bf(tile[tx][ty + i]);
}

// ---------- tiny fp32 transpose for Wb/Wa: [2048,12] -> [12,2048] ----------
__global__ void wtrans_kernel(const float* __restrict__ Wb, const float* __restrict__ Wa,
                              float* __restrict__ WbT, float* __restrict__ WaT) {
    int i = blockIdx.x * 256 + threadIdx.x;   // 0..24575
    int hh = i >> 11, e = i & 2047;
    WbT[i] = Wb[(size_t)e * 12 + hh];
    WaT[i] = Wa[(size_t)e * 12 + hh];
}

// ---------- bf16 GEMM: C[M,N] = A[M,K] * Bt[N,K]^T, fp32 acc ----------
__global__ __launch_bounds__(256) void gemm_bt(const ushort* __restrict__ A,
                                               const ushort* __restrict__ Bt0,
                                               const ushort* __restrict__ Bt1,
                                               void* __restrict__ C0v,
                                               void* __restrict__ C1v,
                                               int M, int N, int K, int out_bf16) {
    const ushort* Bt = blockIdx.z ? Bt1 : Bt0;
    void* Cv = blockIdx.z ? C1v : C0v;
    __shared__ __align__(16) ushort As[128 * 32];
    __shared__ __align__(16) ushort Bs[128 * 32];
    const int tid = threadIdx.x;
    const int m0 = blockIdx.y * 128, n0 = blockIdx.x * 128;

    const int r0 = tid >> 2, cc = (tid & 3) * 8;
    const ushort* ga0 = A  + (size_t)(m0 + r0)      * K + cc;
    const ushort* ga1 = A  + (size_t)(m0 + r0 + 64) * K + cc;
    const ushort* gb0 = Bt + (size_t)(n0 + r0)      * K + cc;
    const ushort* gb1 = Bt + (size_t)(n0 + r0 + 64) * K + cc;
    const int la0 = r0 * 32 + cc, la1 = (r0 + 64) * 32 + cc;

    const int lane = tid & 63;
    const int wid = tid >> 6;
    const int wr = (wid >> 1) * 64, wc = (wid & 1) * 64;
    const int fr = lane & 15, koff = (lane >> 4) * 8;

    f32x4 acc[4][4] = {};
    for (int k0 = 0; k0 < K; k0 += 32) {
        uint4 va0 = *(const uint4*)(ga0 + k0);
        uint4 va1 = *(const uint4*)(ga1 + k0);
        uint4 vb0 = *(const uint4*)(gb0 + k0);
        uint4 vb1 = *(const uint4*)(gb1 + k0);
        __syncthreads();
        *(uint4*)&As[la0] = va0;
        *(uint4*)&As[la1] = va1;
        *(uint4*)&Bs[la0] = vb0;
        *(uint4*)&Bs[la1] = vb1;
        __syncthreads();
        bf16x8 af[4], bf[4];
#pragma unroll
        for (int i = 0; i < 4; ++i) {
            af[i] = *(const bf16x8*)&As[(wr + i * 16 + fr) * 32 + koff];
            bf[i] = *(const bf16x8*)&Bs[(wc + i * 16 + fr) * 32 + koff];
        }
#pragma unroll
        for (int i = 0; i < 4; ++i)
#pragma unroll
            for (int j = 0; j < 4; ++j)
                acc[i][j] = __builtin_amdgcn_mfma_f32_16x16x32_bf16(af[i], bf[j], acc[i][j], 0, 0, 0);
    }
    const int rbase = (lane >> 4) * 4;
    if (out_bf16) {
        ushort* C = (ushort*)Cv;
#pragma unroll
        for (int i = 0; i < 4; ++i)
#pragma unroll
            for (int j = 0; j < 4; ++j)
#pragma unroll
                for (int r = 0; r < 4; ++r)
                    C[(size_t)(m0 + wr + i * 16 + rbase + r) * N + n0 + wc + j * 16 + fr] = f2bf(acc[i][j][r]);
    } else {
        float* C = (float*)Cv;
#pragma unroll
        for (int i = 0; i < 4; ++i)
#pragma unroll
            for (int j = 0; j < 4; ++j)
#pragma unroll
                for (int r = 0; r < 4; ++r)
                    C[(size_t)(m0 + wr + i * 16 + rbase + r) * N + n0 + wc + j * 16 + fr] = acc[i][j][r];
    }
}

// ---------- beta / g projections (coalesced transposed weights) ----------
__global__ __launch_bounds__(256) void bg_kernel(const float* __restrict__ hs,
                                                 const float* __restrict__ WbT,
                                                 const float* __restrict__ WaT,
                                                 const float* __restrict__ A_log,
                                                 const float* __restrict__ dt_bias,
                                                 float* __restrict__ beta,
                                                 float* __restrict__ g) {
    __shared__ float xs[2048];
    int t = blockIdx.x;
    for (int i = threadIdx.x; i < 2048; i += 256) xs[i] = hs[(size_t)t * 2048 + i];
    __syncthreads();
    int w = threadIdx.x >> 6, l = threadIdx.x & 63;
#pragma unroll
    for (int i = 0; i < 6; ++i) {
        int d = w * 6 + i;          // 0..23
        int hh = d % 12;
        const float* W = ((d < 12) ? WbT : WaT) + (size_t)hh * 2048;
        float p = 0.f;
        for (int e = l; e < 2048; e += 64) p += xs[e] * W[e];
#pragma unroll
        for (int m = 32; m >= 1; m >>= 1) p += __shfl_xor(p, m, 64);
        if (l == 0) {
            if (d < 12) {
                beta[t * 12 + hh] = 1.f / (1.f + expf(-p));
            } else {
                float xg = p + dt_bias[hh];
                float sp = (xg > 15.f) ? xg : log1pf(expf(xg));
                g[t * 12 + hh] = -expf(A_log[hh]) * sp;
            }
        }
    }
}

// ---------- causal conv(K=4) + SiLU + l2norm for q/k (reads merged proj) ----------
__global__ void convqk_kernel(const float* __restrict__ proj,
                              const float* __restrict__ cwq, const float* __restrict__ cwk,
                              float* __restrict__ qout, float* __restrict__ kout) {
    int t = blockIdx.x, h = blockIdx.y, which = blockIdx.z;
    const float* x = proj + which * 1536;       // q at col 0, k at col 1536
    const float* cw = which ? cwk : cwq;
    float* out = which ? kout : qout;
    int c = threadIdx.x;                 // 0..127
    int ch = h * 128 + c;
    float4 w = *(const float4*)(cw + (size_t)ch * 4);
    float y = w.w * x[(size_t)t * 9216 + ch];
    if (t >= 1) y += w.z * x[(size_t)(t - 1) * 9216 + ch];
    if (t >= 2) y += w.y * x[(size_t)(t - 2) * 9216 + ch];
    if (t >= 3) y += w.x * x[(size_t)(t - 3) * 9216 + ch];
    y = y / (1.f + __expf(-y));          // silu
    float ss = y * y;
#pragma unroll
    for (int m = 32; m >= 1; m >>= 1) ss += __shfl_xor(ss, m, 64);
    __shared__ float red[2];
    if ((threadIdx.x & 63) == 0) red[threadIdx.x >> 6] = ss;
    __syncthreads();
    float tot = red[0] + red[1];
    out[((size_t)t * 12 + h) * 128 + c] = y * rsqrtf(tot + 1e-6f);
}

// ---------- causal conv(K=4) + SiLU for v (merged proj col 3072) ----------
__global__ void convv_kernel(const float* __restrict__ proj, const float* __restrict__ cwv,
                             float* __restrict__ vout) {
    int t = blockIdx.x, h = blockIdx.y;
    const float* x = proj + 3072;
    int c = threadIdx.x;                 // 0..255
    int ch = h * 256 + c;
    float4 w = *(const float4*)(cwv + (size_t)ch * 4);
    float y = w.w * x[(size_t)t * 9216 + ch];
    if (t >= 1) y += w.z * x[(size_t)(t - 1) * 9216 + ch];
    if (t >= 2) y += w.y * x[(size_t)(t - 2) * 9216 + ch];
    if (t >= 3) y += w.x * x[(size_t)(t - 3) * 9216 + ch];
    y = y / (1.f + __expf(-y));
    vout[((size_t)t * 12 + h) * 256 + c] = y;
}

// ---------- gated delta rule scan (v4b: LDS-staged chunks + DPP reduction) ----------
// 3072 (head, dv) column recurrences; 16 lanes/column (8 dk each), 4 columns/wave,
// one wave per block, 768 blocks. Inputs staged chunk-wise (16 steps) into
// double-buffered LDS via a register burst (T14); sched_barrier(0) pins the burst's
// global loads to issue before the chunk compute (R6 failure: compiler sank them).
__global__ __launch_bounds__(64) void scan_kernel(const float* __restrict__ qn,
                                                  const float* __restrict__ kn,
                                                  const float* __restrict__ vv,
                                                  const float* __restrict__ gd,
                                                  const float* __restrict__ bt,
                                                  float* __restrict__ o) {
    const int b = blockIdx.x;
    const int h = b >> 6;
    const int quad = b & 63;
    const int tid = threadIdx.x;
    const int grp = tid >> 4;
    const int l16 = tid & 15;
    const int dv = quad * 4 + grp;

    __shared__ float kq[2][16][256];    // [t][0..127]=k row, [128..255]=q row
    __shared__ float vgb[2][16][8];     // [t][0..3]=v(4 cols), [4]=g, [5]=b

    const int sh = tid & 31;
    const float* srcA = (tid < 32 ? kn : qn) + h * 128 + sh * 4;  // +t*1536
    const float* vsrc = vv + h * 256 + quad * 4 + (tid & 3);      // +t*3072
    const int vt = tid >> 2;
    const int qoff = (tid >= 32) ? 128 : 0;
    float* op = o + h * 256 + dv;                                 // +t*3072

    float S0 = 0.f, S1 = 0.f, S2 = 0.f, S3 = 0.f, S4 = 0.f, S5 = 0.f, S6 = 0.f, S7 = 0.f;
    float4 kaC, kbC, qaC, qbC; float vC, gC, bC;
    float4 kaN, kbN, qaN, qbN; float vN, gN, bN;
    float4 stg[16]; float vstg, gbstg;

#define ISSUE_STAGE(TC) { \
    const int tc_ = (TC) < 1024 ? (TC) : 1008; \
    _Pragma("unroll") \
    for (int tt = 0; tt < 16; ++tt) \
        stg[tt] = *(const float4*)(srcA + (size_t)(tc_ + tt) * 1536); \
    vstg = vsrc[(size_t)(tc_ + vt) * 3072]; \
    gbstg = 0.f; \
    if (tid < 16) gbstg = gd[(size_t)(tc_ + l16) * 12 + h]; \
    else if (tid < 32) gbstg = bt[(size_t)(tc_ + (tid - 16)) * 12 + h]; \
    __builtin_amdgcn_sched_barrier(0); /* pin burst issue before chunk compute */ }

#define WRITE_STAGE(P) { \
    _Pragma("unroll") \
    for (int tt = 0; tt < 16; ++tt) \
        *(float4*)&kq[P][tt][qoff + sh * 4] = stg[tt]; \
    vgb[P][vt][tid & 3] = vstg; \
    if (tid < 16) vgb[P][l16][4] = gbstg; \
    else if (tid < 32) vgb[P][tid - 16][5] = gbstg; }

#define LDS_READ_C(P, T) { \
    kaC = *(const float4*)&kq[P][T][l16 * 8]; \
    kbC = *(const float4*)&kq[P][T][l16 * 8 + 4]; \
    qaC = *(const float4*)&kq[P][T][128 + l16 * 8]; \
    qbC = *(const float4*)&kq[P][T][128 + l16 * 8 + 4]; \
    vC = vgb[P][T][grp]; gC = vgb[P][T][4]; bC = vgb[P][T][5]; }

#define LDS_READ_N(P, T) { \
    kaN = *(const float4*)&kq[P][T][l16 * 8]; \
    kbN = *(const float4*)&kq[P][T][l16 * 8 + 4]; \
    qaN = *(const float4*)&kq[P][T][128 + l16 * 8]; \
    qbN = *(const float4*)&kq[P][T][128 + l16 * 8 + 4]; \
    vN = vgb[P][T][grp]; gN = vgb[P][T][4]; bN = vgb[P][T][5]; }

#define SHIFT() { kaC = kaN; kbC = kbN; qaC = qaN; qbC = qbN; vC = vN; gC = gN; bC = bN; }

#define STEP(TGLOB) { \
    float d_ = __expf(gC); \
    float p01 = kaC.x * S0 + kaC.y * S1, p23 = kaC.z * S2 + kaC.w * S3; \
    float p45 = kbC.x * S4 + kbC.y * S5, p67 = kbC.z * S6 + kbC.w * S7; \
    float p_ = red16((p01 + p23) + (p45 + p67)); \
    float delta = (vC - d_ * p_) * bC; \
    S0 = d_ * S0 + kaC.x * delta; S1 = d_ * S1 + kaC.y * delta; \
    S2 = d_ * S2 + kaC.z * delta; S3 = d_ * S3 + kaC.w * delta; \
    S4 = d_ * S4 + kbC.x * delta; S5 = d_ * S5 + kbC.y * delta; \
    S6 = d_ * S6 + kbC.z * delta; S7 = d_ * S7 + kbC.w * delta; \
    float o01 = qaC.x * S0 + qaC.y * S1, o23 = qaC.z * S2 + qaC.w * S3; \
    float o45 = qbC.x * S4 + qbC.y * S5, o67 = qbC.z * S6 + qbC.w * S7; \
    float oo = red16((o01 + o23) + (o45 + o67)); \
    if (l16 == 0) op[(size_t)(TGLOB) * 3072] = oo; }

    ISSUE_STAGE(0)
    WRITE_STAGE(0)
    __syncthreads();
    LDS_READ_C(0, 0)

    for (int c = 0; c < 64; ++c) {
        const int p = c & 1;
        ISSUE_STAGE((c + 1) * 16)           // bulk burst for next chunk (covered by compute)
#pragma unroll
        for (int t = 0; t < 16; ++t) {
            if (t < 15) { LDS_READ_N(p, t + 1) }
            STEP(c * 16 + t)
            if (t < 15) { SHIFT() }
        }
        __syncthreads();
        WRITE_STAGE(p ^ 1)
        __syncthreads();
        LDS_READ_C(p ^ 1, 0)
    }
#undef ISSUE_STAGE
#undef WRITE_STAGE
#undef LDS_READ_C
#undef LDS_READ_N
#undef SHIFT
#undef STEP
}

// ---------- RMSNorm * norm_w * silu(gate), bf16 out (gate from merged proj col 6144) ----------
__global__ __launch_bounds__(256) void normgate_kernel(const float* __restrict__ o,
                                                       const float* __restrict__ proj,
                                                       const float* __restrict__ norm_w,
                                                       ushort* __restrict__ on) {
    int t = blockIdx.x, h = blockIdx.y;
    int c = threadIdx.x;                 // 0..255
    float val = o[((size_t)t * 12 + h) * 256 + c];
    float ss = val * val;
#pragma unroll
    for (int m = 32; m >= 1; m >>= 1) ss += __shfl_xor(ss, m, 64);
    __shared__ float red[4];
    if ((threadIdx.x & 63) == 0) red[threadIdx.x >> 6] = ss;
    __syncthreads();
    float tot = red[0] + red[1] + red[2] + red[3];
    float rstd = rsqrtf(tot * (1.f / 256.f) + 1e-5f);
    float gg = proj[(size_t)t * 9216 + 6144 + h * 256 + c];
    float res = val * rstd * norm_w[c] * (gg / (1.f + __expf(-gg)));
    on[(size_t)t * 3072 + h * 256 + c] = f2bf(res);
}

// ---------- launch ----------
extern "C" void kernel_launch(void* const* d_in, const int* in_sizes, int n_in,
                              void* d_out, int out_size, void* d_ws, size_t ws_size,
                              hipStream_t stream) {
    const float* hs   = (const float*)d_in[0];   // [1024,2048]
    const float* Wq   = (const float*)d_in[1];   // [2048,1536]
    const float* Wk   = (const float*)d_in[2];
    const float* Wv   = (const float*)d_in[3];   // [2048,3072]
    const float* Wb   = (const float*)d_in[4];   // [2048,12]
    const float* Wa   = (const float*)d_in[5];
    const float* Wg   = (const float*)d_in[6];   // [2048,3072]
    const float* Wo   = (const float*)d_in[7];   // [3072,2048]
    const float* cwq  = (const float*)d_in[8];   // [1536,4]
    const float* cwk  = (const float*)d_in[9];
    const float* cwv  = (const float*)d_in[10];  // [3072,4]
    const float* A_log   = (const float*)d_in[11];
    const float* dt_bias = (const float*)d_in[12];
    const float* norm_w  = (const float*)d_in[13];
    float* out = (float*)d_out;                  // [1024,2048] fp32

    char* w = (char*)d_ws;
    auto alloc = [&](size_t bytes) { char* p = w; w += (bytes + 255) & ~(size_t)255; return p; };
    ushort* hs_bf   = (ushort*)alloc(1024 * 2048 * 2);
    ushort* WqkvgT  = (ushort*)alloc((size_t)9216 * 2048 * 2);  // [q|k|v|g] rows
    ushort* WoT     = (ushort*)alloc((size_t)2048 * 3072 * 2);
    float* proj     = (float*)alloc((size_t)1024 * 9216 * 4);   // merged projections
    float* qn       = (float*)alloc((size_t)1024 * 1536 * 4);
    float* kn       = (float*)alloc((size_t)1024 * 1536 * 4);
    float* vn       = (float*)alloc((size_t)1024 * 3072 * 4);
    float* gdec     = (float*)alloc(1024 * 12 * 4);
    float* betab    = (float*)alloc(1024 * 12 * 4);
    float* ob       = (float*)alloc((size_t)1024 * 3072 * 4);
    ushort* onb     = (ushort*)alloc((size_t)1024 * 3072 * 2);
    float* WbT      = (float*)alloc(12 * 2048 * 4);
    float* WaT      = (float*)alloc(12 * 2048 * 4);
    (void)ws_size; (void)n_in; (void)in_sizes; (void)out_size;

    // casts / transposes (concatenated weight: q@0, k@1536, v@3072, g@6144)
    cast_bf16x4<<<2048, 256, 0, stream>>>((const float4*)hs, (ushort4*)hs_bf, 1024 * 2048 / 4);
    transpose_cast<<<dim3(48, 64), 256, 0, stream>>>(Wq, WqkvgT, 2048, 1536);
    transpose_cast<<<dim3(48, 64), 256, 0, stream>>>(Wk, WqkvgT + (size_t)1536 * 2048, 2048, 1536);
    transpose_cast<<<dim3(96, 64), 256, 0, stream>>>(Wv, WqkvgT + (size_t)3072 * 2048, 2048, 3072);
    transpose_cast<<<dim3(96, 64), 256, 0, stream>>>(Wg, WqkvgT + (size_t)6144 * 2048, 2048, 3072);
    transpose_cast<<<dim3(64, 96), 256, 0, stream>>>(Wo, WoT, 3072, 2048);
    wtrans_kernel<<<96, 256, 0, stream>>>(Wb, Wa, WbT, WaT);

    // merged q/k/v/g projection: [1024,2048] x [2048,9216]
    gemm_bt<<<dim3(72, 8, 1), 256, 0, stream>>>(hs_bf, WqkvgT, WqkvgT, proj, proj, 1024, 9216, 2048, 0);
    bg_kernel<<<1024, 256, 0, stream>>>(hs, WbT, WaT, A_log, dt_bias, betab, gdec);

    // conv + silu (+ l2norm for q/k)
    convqk_kernel<<<dim3(1024, 12, 2), 128, 0, stream>>>(proj, cwq, cwk, qn, kn);
    convv_kernel<<<dim3(1024, 12), 256, 0, stream>>>(proj, cwv, vn);

    // gated delta rule
    scan_kernel<<<768, 64, 0, stream>>>(qn, kn, vn, gdec, betab, ob);

    // norm + gate -> bf16 (A operand of final GEMM)
    normgate_kernel<<<dim3(1024, 12), 256, 0, stream>>>(ob, proj, norm_w, onb);

    // output projection -> fp32 d_out
    gemm_bt<<<dim3(16, 8, 1), 256, 0, stream>>>(onb, WoT, WoT, (void*)out, (void*)out, 1024, 2048, 3072, 0);
}